// Round 1
// baseline (682.349 us; speedup 1.0000x reference)
//
#include <hip/hip_runtime.h>
#include <math.h>
#include <stdint.h>

#define NN 50000
#define NE 200000
#define HD 768
#define TWOH 1536
#define DD1 256
#define BM 128
#define BK 64
#define KSTEPS 24   // TWOH / BK

typedef __bf16 bf16_t;
typedef __attribute__((ext_vector_type(8))) __bf16 bf16x8;
typedef __attribute__((ext_vector_type(4))) float f32x4;

__device__ __forceinline__ void gl2lds16(const void* g, void* l) {
    __builtin_amdgcn_global_load_lds(
        (const __attribute__((address_space(1))) unsigned int*)g,
        (__attribute__((address_space(3))) unsigned int*)l,
        16, 0, 0);
}

// ---- f32 -> bf16 cast, 8 elems/thread ----
__global__ void cvt8_kernel(const float* __restrict__ in, bf16_t* __restrict__ out, int n8) {
    int i = blockIdx.x * blockDim.x + threadIdx.x;
    if (i >= n8) return;
    const float4* p = (const float4*)in + (size_t)i * 2;
    float4 a = p[0], b = p[1];
    bf16x8 o;
    o[0]=(bf16_t)a.x; o[1]=(bf16_t)a.y; o[2]=(bf16_t)a.z; o[3]=(bf16_t)a.w;
    o[4]=(bf16_t)b.x; o[5]=(bf16_t)b.y; o[6]=(bf16_t)b.z; o[7]=(bf16_t)b.w;
    *(bf16x8*)(out + (size_t)i * 8) = o;
}

__global__ void finalize_kernel(float* __restrict__ out, const float* __restrict__ accum) {
    out[0] = accum[0] / accum[1];
}

// ---- fused: gather -> GEMM1(bf16 MFMA) -> gelu -> GEMM2 -> softmax/CE ----
template<bool XPRE, bool WPRE>
__global__ __launch_bounds__(512, 4)
void fused_edge_mlp(const float* __restrict__ xf, const bf16_t* __restrict__ xb,
                    const float* __restrict__ w1f, const bf16_t* __restrict__ w1b,
                    const float* __restrict__ b1, const float* __restrict__ w2,
                    const float* __restrict__ b2, const float* __restrict__ cw,
                    const int* __restrict__ esrc, const int* __restrict__ edst,
                    const int* __restrict__ lab, float* __restrict__ out,
                    float* __restrict__ accum)
{
    // Phase 1: A [8 kc][128 m][8] bf16 = 16KB ; B [8 kc][256 n][8] bf16 = 32KB
    // Phase 2 (union): H [64 m][256] bf16 = 32KB (per half-tile)
    __shared__ __align__(16) char smem[49152];
    __shared__ float red[16];
    bf16_t* Al = (bf16_t*)smem;
    bf16_t* Bl = (bf16_t*)(smem + 16384);
    bf16_t* Hl = (bf16_t*)smem;

    const int t = threadIdx.x;
    const int lane = t & 63;
    const int wv = t >> 6;        // 0..7
    const int wm = wv & 1;        // m-half of the 128-edge tile
    const int wn = wv >> 1;       // 64-col quarter of D1=256
    const int q = lane >> 4;      // 0..3
    const int r = lane & 15;

    const int ebase = blockIdx.x * BM;
    const int am = t & 127;       // A row this thread stages
    const int eidx = ebase + am;
    const bool ev = eidx < NE;
    const int nsrc = ev ? esrc[eidx] : 0;
    const int ndst = ev ? edst[eidx] : 0;

    f32x4 acc[4][4];
    #pragma unroll
    for (int a_ = 0; a_ < 4; ++a_)
        #pragma unroll
        for (int b_ = 0; b_ < 4; ++b_) acc[a_][b_] = (f32x4){0.f, 0.f, 0.f, 0.f};

    const int akc0 = t >> 7;      // 0..3
    const int bn   = t & 255;     // B row (n)
    const int bkc0 = t >> 8;      // 0..1

    for (int ks = 0; ks < KSTEPS; ++ks) {
        const int k0 = ks * BK;
        const int node = (k0 < HD) ? nsrc : ndst;
        const int col0 = (k0 < HD) ? k0 : (k0 - HD);
        __syncthreads();   // previous compute done before overwrite
        // ---- stage A (gathered node rows), 2 chunks/thread ----
        #pragma unroll
        for (int i = 0; i < 2; ++i) {
            const int kc = i * 4 + akc0;
            bf16_t* lp = Al + (size_t)((kc << 7) + am) * 8;
            if (XPRE) {
                const bf16_t* gp = xb + (size_t)node * HD + col0 + kc * 8;
                gl2lds16(gp, lp);
            } else {
                const float* gp = xf + (size_t)node * HD + col0 + kc * 8;
                float4 v0 = ((const float4*)gp)[0];
                float4 v1 = ((const float4*)gp)[1];
                bf16x8 o;
                o[0]=(bf16_t)v0.x; o[1]=(bf16_t)v0.y; o[2]=(bf16_t)v0.z; o[3]=(bf16_t)v0.w;
                o[4]=(bf16_t)v1.x; o[5]=(bf16_t)v1.y; o[6]=(bf16_t)v1.z; o[7]=(bf16_t)v1.w;
                *(bf16x8*)lp = o;
            }
        }
        // ---- stage B (W1 rows), 4 chunks/thread ----
        #pragma unroll
        for (int i = 0; i < 4; ++i) {
            const int kc = i * 2 + bkc0;
            bf16_t* lp = Bl + (size_t)((kc << 8) + bn) * 8;
            if (WPRE) {
                const bf16_t* gp = w1b + (size_t)bn * TWOH + k0 + kc * 8;
                gl2lds16(gp, lp);
            } else {
                const float* gp = w1f + (size_t)bn * TWOH + k0 + kc * 8;
                float4 v0 = ((const float4*)gp)[0];
                float4 v1 = ((const float4*)gp)[1];
                bf16x8 o;
                o[0]=(bf16_t)v0.x; o[1]=(bf16_t)v0.y; o[2]=(bf16_t)v0.z; o[3]=(bf16_t)v0.w;
                o[4]=(bf16_t)v1.x; o[5]=(bf16_t)v1.y; o[6]=(bf16_t)v1.z; o[7]=(bf16_t)v1.w;
                *(bf16x8*)lp = o;
            }
        }
        __syncthreads();
        // ---- MFMA inner loop ----
        #pragma unroll
        for (int kk = 0; kk < 2; ++kk) {
            bf16x8 af[4];
            #pragma unroll
            for (int mb = 0; mb < 4; ++mb)
                af[mb] = *(const bf16x8*)(Al + (size_t)((((kk * 4 + q) << 7) + wm * 64 + mb * 16 + r)) * 8);
            #pragma unroll
            for (int nb = 0; nb < 4; ++nb) {
                bf16x8 bfr = *(const bf16x8*)(Bl + (size_t)((((kk * 4 + q) << 8) + wn * 64 + nb * 16 + r)) * 8);
                #pragma unroll
                for (int mb = 0; mb < 4; ++mb)
                    acc[mb][nb] = __builtin_amdgcn_mfma_f32_16x16x32_bf16(af[mb], bfr, acc[mb][nb], 0, 0, 0);
            }
        }
    }

    // ---- epilogue: bias + exact gelu -> H (bf16, xor-swizzled) -> GEMM2 -> softmax/CE ----
    float bias[4];
    #pragma unroll
    for (int nb = 0; nb < 4; ++nb) bias[nb] = b1[wn * 64 + nb * 16 + r];

    float wnll_t = 0.f, wsum_t = 0.f;
    const int ml2 = t >> 3;       // 0..63 edge within half-tile
    const int p = t & 7;          // 8 threads per edge

    #pragma unroll
    for (int half = 0; half < 2; ++half) {
        __syncthreads();          // protect previous phase users of smem
        if (wm == half) {
            #pragma unroll
            for (int mb = 0; mb < 4; ++mb)
                #pragma unroll
                for (int nb = 0; nb < 4; ++nb)
                    #pragma unroll
                    for (int rr = 0; rr < 4; ++rr) {
                        int ml = mb * 16 + q * 4 + rr;          // 0..63
                        int col = wn * 64 + nb * 16 + r;        // 0..255
                        float v = acc[mb][nb][rr] + bias[nb];
                        float g = 0.5f * v * (1.f + erff(v * 0.70710678118654752f));
                        int swcol = ((((col >> 3) ^ (ml & 7)) << 3) | (col & 7));
                        Hl[ml * 256 + swcol] = (bf16_t)g;
                    }
        }
        __syncthreads();
        float l0 = 0.f, l1 = 0.f;
        #pragma unroll
        for (int j = 0; j < 4; ++j) {
            int cj = p * 4 + j;
            bf16x8 hv = *(const bf16x8*)(Hl + ml2 * 256 + ((cj ^ (ml2 & 7)) << 3));
            const float4* w2a = (const float4*)(w2 + cj * 8);
            const float4* w2b = (const float4*)(w2 + 256 + cj * 8);
            float4 wa0 = w2a[0], wa1 = w2a[1], wb0 = w2b[0], wb1 = w2b[1];
            float hf[8];
            #pragma unroll
            for (int u = 0; u < 8; ++u) hf[u] = (float)hv[u];
            l0 += hf[0]*wa0.x + hf[1]*wa0.y + hf[2]*wa0.z + hf[3]*wa0.w
                + hf[4]*wa1.x + hf[5]*wa1.y + hf[6]*wa1.z + hf[7]*wa1.w;
            l1 += hf[0]*wb0.x + hf[1]*wb0.y + hf[2]*wb0.z + hf[3]*wb0.w
                + hf[4]*wb1.x + hf[5]*wb1.y + hf[6]*wb1.z + hf[7]*wb1.w;
        }
        l0 += __shfl_xor(l0, 1); l0 += __shfl_xor(l0, 2); l0 += __shfl_xor(l0, 4);
        l1 += __shfl_xor(l1, 1); l1 += __shfl_xor(l1, 2); l1 += __shfl_xor(l1, 4);
        const int eg = ebase + half * 64 + ml2;
        if (p == 0 && eg < NE) {
            l0 += b2[0]; l1 += b2[1];
            float mx = fmaxf(l0, l1);
            float e0 = expf(l0 - mx), e1 = expf(l1 - mx);
            float s = e0 + e1;
            float inv = 1.f / s;
            out[1 + 2 * eg] = e0 * inv;
            out[2 + 2 * eg] = e1 * inv;
            int lb = lab[eg];
            float w = cw[lb];
            float lpv = ((lb ? l1 : l0) - mx) - logf(s);
            wnll_t -= w * lpv;
            wsum_t += w;
        }
    }
    // block reduction -> 2 atomics/block
    #pragma unroll
    for (int o = 1; o < 64; o <<= 1) {
        wnll_t += __shfl_xor(wnll_t, o);
        wsum_t += __shfl_xor(wsum_t, o);
    }
    if (lane == 0) { red[wv] = wnll_t; red[8 + wv] = wsum_t; }
    __syncthreads();
    if (t == 0) {
        float a_ = 0.f, b_ = 0.f;
        #pragma unroll
        for (int i = 0; i < 8; ++i) { a_ += red[i]; b_ += red[8 + i]; }
        atomicAdd(&accum[0], a_);
        atomicAdd(&accum[1], b_);
    }
}

extern "C" void kernel_launch(void* const* d_in, const int* in_sizes, int n_in,
                              void* d_out, int out_size, void* d_ws, size_t ws_size,
                              hipStream_t stream)
{
    (void)in_sizes; (void)n_in; (void)out_size;
    const float* x  = (const float*)d_in[0];
    const float* W1 = (const float*)d_in[1];
    const float* b1 = (const float*)d_in[2];
    const float* W2 = (const float*)d_in[3];
    const float* b2 = (const float*)d_in[4];
    const float* cw = (const float*)d_in[5];
    const int* esrc = (const int*)d_in[6];
    const int* edst = (const int*)d_in[7];
    const int* lab  = (const int*)d_in[8];
    float* out = (float*)d_out;
    char* ws = (char*)d_ws;

    float* accum = (float*)ws;
    const size_t off_w1 = 256;
    const size_t w1_bytes = (size_t)DD1 * TWOH * 2;     // 786432
    const size_t off_x = off_w1 + w1_bytes;             // 786688 (16B aligned)
    const size_t x_bytes = (size_t)NN * HD * 2;         // 76.8 MB
    bf16_t* w1b = (bf16_t*)(ws + off_w1);
    bf16_t* xb  = (bf16_t*)(ws + off_x);
    const bool wpre = ws_size >= off_w1 + w1_bytes;
    const bool xpre = ws_size >= off_x + x_bytes;

    hipMemsetAsync(accum, 0, 2 * sizeof(float), stream);
    if (wpre) {
        int n8 = DD1 * TWOH / 8;
        cvt8_kernel<<<(n8 + 255) / 256, 256, 0, stream>>>(W1, w1b, n8);
    }
    if (xpre) {
        int n8 = NN * HD / 8;
        cvt8_kernel<<<(n8 + 255) / 256, 256, 0, stream>>>(x, xb, n8);
    }

    dim3 grid((NE + BM - 1) / BM);
    if (xpre && wpre)
        fused_edge_mlp<true, true><<<grid, 512, 0, stream>>>(x, xb, W1, w1b, b1, W2, b2, cw, esrc, edst, lab, out, accum);
    else if (wpre)
        fused_edge_mlp<false, true><<<grid, 512, 0, stream>>>(x, xb, W1, w1b, b1, W2, b2, cw, esrc, edst, lab, out, accum);
    else
        fused_edge_mlp<false, false><<<grid, 512, 0, stream>>>(x, xb, W1, w1b, b1, W2, b2, cw, esrc, edst, lab, out, accum);

    finalize_kernel<<<1, 1, 0, stream>>>(out, accum);
}

// Round 3
// 660.825 us; speedup vs baseline: 1.0326x; 1.0326x over previous
//
#include <hip/hip_runtime.h>
#include <math.h>
#include <stdint.h>

#define NN 50000
#define NE 200000
#define HD 768
#define TWOH 1536
#define DD1 256
#define BM 128
#define BK 64
#define KSTEPS 24   // TWOH / BK

typedef __bf16 bf16_t;
typedef __attribute__((ext_vector_type(8))) __bf16 bf16x8;
typedef __attribute__((ext_vector_type(4))) float f32x4;

__device__ __forceinline__ void gl2lds16(const void* g, void* l) {
    __builtin_amdgcn_global_load_lds(
        (const __attribute__((address_space(1))) unsigned int*)g,
        (__attribute__((address_space(3))) unsigned int*)l,
        16, 0, 0);
}

// ---- f32 -> bf16 cast, 16 elems/thread (2 independent 32B loads for ILP) ----
__global__ void cvt16_kernel(const float* __restrict__ in, bf16_t* __restrict__ out, int n16) {
    int i = blockIdx.x * blockDim.x + threadIdx.x;
    if (i >= n16) return;
    const float4* p = (const float4*)in + (size_t)i * 4;
    float4 a = p[0], b = p[1], c = p[2], d = p[3];
    bf16x8 o0, o1;
    o0[0]=(bf16_t)a.x; o0[1]=(bf16_t)a.y; o0[2]=(bf16_t)a.z; o0[3]=(bf16_t)a.w;
    o0[4]=(bf16_t)b.x; o0[5]=(bf16_t)b.y; o0[6]=(bf16_t)b.z; o0[7]=(bf16_t)b.w;
    o1[0]=(bf16_t)c.x; o1[1]=(bf16_t)c.y; o1[2]=(bf16_t)c.z; o1[3]=(bf16_t)c.w;
    o1[4]=(bf16_t)d.x; o1[5]=(bf16_t)d.y; o1[6]=(bf16_t)d.z; o1[7]=(bf16_t)d.w;
    bf16x8* q = (bf16x8*)(out + (size_t)i * 16);
    q[0] = o0; q[1] = o1;
}

__global__ void finalize_kernel(float* __restrict__ out, const float* __restrict__ accum) {
    out[0] = accum[0] / accum[1];
}

// ---- fused: gather -> GEMM1(bf16 MFMA, A-double-buffered pipeline) -> gelu -> GEMM2 -> softmax/CE ----
template<bool XPRE, bool WPRE>
__global__ __launch_bounds__(512, 4)
void fused_edge_mlp(const float* __restrict__ xf, const bf16_t* __restrict__ xb,
                    const float* __restrict__ w1f, const bf16_t* __restrict__ w1b,
                    const float* __restrict__ b1, const float* __restrict__ w2,
                    const float* __restrict__ b2, const float* __restrict__ cw,
                    const int* __restrict__ esrc, const int* __restrict__ edst,
                    const int* __restrict__ lab, float* __restrict__ out,
                    float* __restrict__ accum)
{
    // K-loop:   A0[8kc][128m][8] 16KB @0 | A1 16KB @16384 | B[8kc][256n][8] 32KB @32768 = 64KB
    // Epilogue: H[64m][256] 32KB over A0+A1 ; red over B region
    __shared__ __align__(16) char smem[65536];

    const int t = threadIdx.x;
    const int lane = t & 63;
    const int wv = t >> 6;        // 0..7
    const int wm = wv & 1;        // m-half of the 128-edge tile
    const int wn = wv >> 1;       // 64-col quarter of D1=256
    const int q = lane >> 4;      // 0..3
    const int r = lane & 15;

    const int ebase = blockIdx.x * BM;
    const int am = t & 127;       // A row this thread stages
    const int eidx = ebase + am;
    const bool ev = eidx < NE;
    const int nsrc = ev ? esrc[eidx] : 0;
    const int ndst = ev ? edst[eidx] : 0;

    const int akc0 = t >> 7;      // 0..3
    const int bn   = t & 255;     // B row (n)
    const int bkc0 = t >> 8;      // 0..1

    f32x4 acc[4][4];
    #pragma unroll
    for (int a_ = 0; a_ < 4; ++a_)
        #pragma unroll
        for (int b_ = 0; b_ < 4; ++b_) acc[a_][b_] = (f32x4){0.f, 0.f, 0.f, 0.f};

    auto stageA = [&](int kp, bf16_t* Ab) {
        const int node = (kp < 12) ? nsrc : ndst;
        const int col0 = (kp < 12) ? kp * BK : kp * BK - HD;
        #pragma unroll
        for (int i = 0; i < 2; ++i) {
            const int kc = i * 4 + akc0;
            bf16_t* lp = Ab + (size_t)((kc << 7) + am) * 8;
            if (XPRE) {
                gl2lds16(xb + (size_t)node * HD + col0 + kc * 8, lp);
            } else {
                const float* gp = xf + (size_t)node * HD + col0 + kc * 8;
                float4 v0 = ((const float4*)gp)[0];
                float4 v1 = ((const float4*)gp)[1];
                bf16x8 o;
                o[0]=(bf16_t)v0.x; o[1]=(bf16_t)v0.y; o[2]=(bf16_t)v0.z; o[3]=(bf16_t)v0.w;
                o[4]=(bf16_t)v1.x; o[5]=(bf16_t)v1.y; o[6]=(bf16_t)v1.z; o[7]=(bf16_t)v1.w;
                *(bf16x8*)lp = o;
            }
        }
    };

    // prologue: A(0) -> A0
    stageA(0, (bf16_t*)smem);

    for (int ks = 0; ks < KSTEPS; ++ks) {
        bf16_t* Ac = (bf16_t*)(smem + ((ks & 1) << 14));
        bf16_t* An = (bf16_t*)(smem + ((~ks & 1) << 14));
        bf16_t* Bl = (bf16_t*)(smem + 32768);
        const int k0 = ks * BK;

        // barrier 1: all waves done reading LDS of step ks-1; compiler's
        // vmcnt(0) drain here waits A(ks) (needed before MFMA anyway).
        __syncthreads();

        // ---- stage B(ks) (W1 rows), 4 chunks/thread ----
        #pragma unroll
        for (int i = 0; i < 4; ++i) {
            const int kc = i * 2 + bkc0;
            bf16_t* lp = Bl + (size_t)((kc << 8) + bn) * 8;
            if (WPRE) {
                gl2lds16(w1b + (size_t)bn * TWOH + k0 + kc * 8, lp);
            } else {
                const float* gp = w1f + (size_t)bn * TWOH + k0 + kc * 8;
                float4 v0 = ((const float4*)gp)[0];
                float4 v1 = ((const float4*)gp)[1];
                bf16x8 o;
                o[0]=(bf16_t)v0.x; o[1]=(bf16_t)v0.y; o[2]=(bf16_t)v0.z; o[3]=(bf16_t)v0.w;
                o[4]=(bf16_t)v1.x; o[5]=(bf16_t)v1.y; o[6]=(bf16_t)v1.z; o[7]=(bf16_t)v1.w;
                *(bf16x8*)lp = o;
            }
        }

        // barrier 2: wait ONLY B (no A(ks+1) in flight yet -> vmcnt(0) is
        // exactly the B wait). Raw s_barrier: only vmem (gl2lds) outstanding.
        if (XPRE && WPRE)
            asm volatile("s_waitcnt vmcnt(0)\n\ts_barrier" ::: "memory");
        else
            __syncthreads();

        // ---- MFMA inner loop on Ac / Bl ----
        #pragma unroll
        for (int kk = 0; kk < 2; ++kk) {
            bf16x8 af[4];
            #pragma unroll
            for (int mb = 0; mb < 4; ++mb)
                af[mb] = *(const bf16x8*)(Ac + (size_t)((((kk * 4 + q) << 7) + wm * 64 + mb * 16 + r)) * 8);
            #pragma unroll
            for (int nb = 0; nb < 4; ++nb) {
                bf16x8 bfr = *(const bf16x8*)(Bl + (size_t)((((kk * 4 + q) << 8) + wn * 64 + nb * 16 + r)) * 8);
                #pragma unroll
                for (int mb = 0; mb < 4; ++mb)
                    acc[mb][nb] = __builtin_amdgcn_mfma_f32_16x16x32_bf16(af[mb], bfr, acc[mb][nb], 0, 0, 0);
            }
        }

        // pin the A(ks+1) prefetch AFTER the fragment ds_reads so the
        // waitcnt legalizer never waits on it before the MFMAs.
        asm volatile("" ::: "memory");
        const int kp = (ks + 1 < KSTEPS) ? ks + 1 : ks;  // last iter: dummy into unused buffer
        stageA(kp, An);
    }

    // ---- epilogue: bias + exact gelu -> H (bf16, xor-swizzled) -> GEMM2 -> softmax/CE ----
    bf16_t* Hl = (bf16_t*)smem;
    float* red = (float*)(smem + 32768);

    float bias[4];
    #pragma unroll
    for (int nb = 0; nb < 4; ++nb) bias[nb] = b1[wn * 64 + nb * 16 + r];

    float wnll_t = 0.f, wsum_t = 0.f;
    const int ml2 = t >> 3;       // 0..63 edge within half-tile
    const int p = t & 7;          // 8 threads per edge

    #pragma unroll
    for (int half = 0; half < 2; ++half) {
        __syncthreads();          // drains vmcnt: dummy prefetch lands before H writes
        if (wm == half) {
            #pragma unroll
            for (int mb = 0; mb < 4; ++mb)
                #pragma unroll
                for (int nb = 0; nb < 4; ++nb)
                    #pragma unroll
                    for (int rr = 0; rr < 4; ++rr) {
                        int ml = mb * 16 + q * 4 + rr;          // 0..63
                        int col = wn * 64 + nb * 16 + r;        // 0..255
                        float v = acc[mb][nb][rr] + bias[nb];
                        float g = 0.5f * v * (1.f + erff(v * 0.70710678118654752f));
                        int swcol = ((((col >> 3) ^ (ml & 7)) << 3) | (col & 7));
                        Hl[ml * 256 + swcol] = (bf16_t)g;
                    }
        }
        __syncthreads();
        float l0 = 0.f, l1 = 0.f;
        #pragma unroll
        for (int j = 0; j < 4; ++j) {
            int cj = p * 4 + j;
            bf16x8 hv = *(const bf16x8*)(Hl + ml2 * 256 + ((cj ^ (ml2 & 7)) << 3));
            const float4* w2a = (const float4*)(w2 + cj * 8);
            const float4* w2b = (const float4*)(w2 + 256 + cj * 8);
            float4 wa0 = w2a[0], wa1 = w2a[1], wb0 = w2b[0], wb1 = w2b[1];
            float hf[8];
            #pragma unroll
            for (int u = 0; u < 8; ++u) hf[u] = (float)hv[u];
            l0 += hf[0]*wa0.x + hf[1]*wa0.y + hf[2]*wa0.z + hf[3]*wa0.w
                + hf[4]*wa1.x + hf[5]*wa1.y + hf[6]*wa1.z + hf[7]*wa1.w;
            l1 += hf[0]*wb0.x + hf[1]*wb0.y + hf[2]*wb0.z + hf[3]*wb0.w
                + hf[4]*wb1.x + hf[5]*wb1.y + hf[6]*wb1.z + hf[7]*wb1.w;
        }
        l0 += __shfl_xor(l0, 1); l0 += __shfl_xor(l0, 2); l0 += __shfl_xor(l0, 4);
        l1 += __shfl_xor(l1, 1); l1 += __shfl_xor(l1, 2); l1 += __shfl_xor(l1, 4);
        const int eg = ebase + half * 64 + ml2;
        if (p == 0 && eg < NE) {
            l0 += b2[0]; l1 += b2[1];
            float mx = fmaxf(l0, l1);
            float e0 = expf(l0 - mx), e1 = expf(l1 - mx);
            float s = e0 + e1;
            float inv = 1.f / s;
            out[1 + 2 * eg] = e0 * inv;
            out[2 + 2 * eg] = e1 * inv;
            int lb = lab[eg];
            float w = cw[lb];
            float lpv = ((lb ? l1 : l0) - mx) - logf(s);
            wnll_t -= w * lpv;
            wsum_t += w;
        }
    }
    // block reduction -> 2 atomics/block
    #pragma unroll
    for (int o = 1; o < 64; o <<= 1) {
        wnll_t += __shfl_xor(wnll_t, o);
        wsum_t += __shfl_xor(wsum_t, o);
    }
    __syncthreads();              // Hl reads done before red writes (red aliases B region; keep ordering safe)
    if (lane == 0) { red[wv] = wnll_t; red[8 + wv] = wsum_t; }
    __syncthreads();
    if (t == 0) {
        float a_ = 0.f, b_ = 0.f;
        #pragma unroll
        for (int i = 0; i < 8; ++i) { a_ += red[i]; b_ += red[8 + i]; }
        atomicAdd(&accum[0], a_);
        atomicAdd(&accum[1], b_);
    }
}

extern "C" void kernel_launch(void* const* d_in, const int* in_sizes, int n_in,
                              void* d_out, int out_size, void* d_ws, size_t ws_size,
                              hipStream_t stream)
{
    (void)in_sizes; (void)n_in; (void)out_size;
    const float* x  = (const float*)d_in[0];
    const float* W1 = (const float*)d_in[1];
    const float* b1 = (const float*)d_in[2];
    const float* W2 = (const float*)d_in[3];
    const float* b2 = (const float*)d_in[4];
    const float* cw = (const float*)d_in[5];
    const int* esrc = (const int*)d_in[6];
    const int* edst = (const int*)d_in[7];
    const int* lab  = (const int*)d_in[8];
    float* out = (float*)d_out;
    char* ws = (char*)d_ws;

    float* accum = (float*)ws;
    const size_t off_w1 = 256;
    const size_t w1_bytes = (size_t)DD1 * TWOH * 2;     // 786432
    const size_t off_x = off_w1 + w1_bytes;             // 786688 (16B aligned)
    const size_t x_bytes = (size_t)NN * HD * 2;         // 76.8 MB
    bf16_t* w1b = (bf16_t*)(ws + off_w1);
    bf16_t* xb  = (bf16_t*)(ws + off_x);
    const bool wpre = ws_size >= off_w1 + w1_bytes;
    const bool xpre = ws_size >= off_x + x_bytes;

    (void)hipMemsetAsync(accum, 0, 2 * sizeof(float), stream);
    if (wpre) {
        int n16 = DD1 * TWOH / 16;
        cvt16_kernel<<<(n16 + 255) / 256, 256, 0, stream>>>(W1, w1b, n16);
    }
    if (xpre) {
        int n16 = NN * HD / 16;
        cvt16_kernel<<<(n16 + 255) / 256, 256, 0, stream>>>(x, xb, n16);
    }

    dim3 grid((NE + BM - 1) / BM);
    if (xpre && wpre)
        fused_edge_mlp<true, true><<<grid, 512, 0, stream>>>(x, xb, W1, w1b, b1, W2, b2, cw, esrc, edst, lab, out, accum);
    else if (wpre)
        fused_edge_mlp<false, true><<<grid, 512, 0, stream>>>(x, xb, W1, w1b, b1, W2, b2, cw, esrc, edst, lab, out, accum);
    else
        fused_edge_mlp<false, false><<<grid, 512, 0, stream>>>(x, xb, W1, w1b, b1, W2, b2, cw, esrc, edst, lab, out, accum);

    finalize_kernel<<<1, 1, 0, stream>>>(out, accum);
}

// Round 4
// 512.661 us; speedup vs baseline: 1.3310x; 1.2890x over previous
//
#include <hip/hip_runtime.h>
#include <math.h>
#include <stdint.h>

#define NN 50000
#define NE 200000
#define HD 768
#define TWOH 1536
#define DD1 256
#define BM 128
#define BK 64
#define KSTEPS 24   // TWOH / BK

typedef __bf16 bf16_t;
typedef __attribute__((ext_vector_type(8))) __bf16 bf16x8;
typedef __attribute__((ext_vector_type(4))) float f32x4;

__device__ __forceinline__ void gl2lds16(const void* g, void* l) {
    __builtin_amdgcn_global_load_lds(
        (const __attribute__((address_space(1))) unsigned int*)g,
        (__attribute__((address_space(3))) unsigned int*)l,
        16, 0, 0);
}

// ---- f32 -> bf16 cast, 16 elems/thread ----
__global__ void cvt16_kernel(const float* __restrict__ in, bf16_t* __restrict__ out, int n16) {
    int i = blockIdx.x * blockDim.x + threadIdx.x;
    if (i >= n16) return;
    const float4* p = (const float4*)in + (size_t)i * 4;
    float4 a = p[0], b = p[1], c = p[2], d = p[3];
    bf16x8 o0, o1;
    o0[0]=(bf16_t)a.x; o0[1]=(bf16_t)a.y; o0[2]=(bf16_t)a.z; o0[3]=(bf16_t)a.w;
    o0[4]=(bf16_t)b.x; o0[5]=(bf16_t)b.y; o0[6]=(bf16_t)b.z; o0[7]=(bf16_t)b.w;
    o1[0]=(bf16_t)c.x; o1[1]=(bf16_t)c.y; o1[2]=(bf16_t)c.z; o1[3]=(bf16_t)c.w;
    o1[4]=(bf16_t)d.x; o1[5]=(bf16_t)d.y; o1[6]=(bf16_t)d.z; o1[7]=(bf16_t)d.w;
    bf16x8* q = (bf16x8*)(out + (size_t)i * 16);
    q[0] = o0; q[1] = o1;
}

// ---- W1 f32 -> bf16, pre-swizzled into main-loop LDS image order [ks][kc][n][8] ----
__global__ void swz_w1_kernel(const float* __restrict__ w1, bf16_t* __restrict__ w1s) {
    int idx = blockIdx.x * blockDim.x + threadIdx.x;   // 0 .. KSTEPS*8*256
    if (idx >= KSTEPS * 8 * 256) return;
    int n  = idx & 255;
    int kc = (idx >> 8) & 7;
    int ks = idx >> 11;
    const float* gp = w1 + (size_t)n * TWOH + ks * BK + kc * 8;
    float4 v0 = ((const float4*)gp)[0];
    float4 v1 = ((const float4*)gp)[1];
    bf16x8 o;
    o[0]=(bf16_t)v0.x; o[1]=(bf16_t)v0.y; o[2]=(bf16_t)v0.z; o[3]=(bf16_t)v0.w;
    o[4]=(bf16_t)v1.x; o[5]=(bf16_t)v1.y; o[6]=(bf16_t)v1.z; o[7]=(bf16_t)v1.w;
    *(bf16x8*)(w1s + (size_t)idx * 8) = o;
}

__global__ void finalize_kernel(float* __restrict__ out, const float* __restrict__ accum) {
    out[0] = accum[0] / accum[1];
}

// ---- fused: gather -> GEMM1(bf16 MFMA, pipelined) -> gelu -> GEMM2 -> softmax/CE ----
template<bool XPRE, bool WPRE>
__global__ __launch_bounds__(512, 4)
void fused_edge_mlp(const float* __restrict__ xf, const bf16_t* __restrict__ xb,
                    const float* __restrict__ w1f, const bf16_t* __restrict__ w1s,
                    const float* __restrict__ b1, const float* __restrict__ w2,
                    const float* __restrict__ b2, const float* __restrict__ cw,
                    const int* __restrict__ esrc, const int* __restrict__ edst,
                    const int* __restrict__ lab, float* __restrict__ out,
                    float* __restrict__ accum)
{
    // K-loop: A0[128m][64k] 16KB @0 | A1 16KB @16384 | B[8kc][256n][8] 32KB @32768 = 64KB
    //   A row-major, chunk c of row m stored at slot c^(m&7) (xor swizzle for bank spread;
    //   global side permutes within the same contiguous 128B -> coalescing unharmed).
    // Epilogue: H[64m][256] 32KB over A0+A1 ; red over B region
    __shared__ __align__(16) char smem[65536];

    const int t = threadIdx.x;
    const int lane = t & 63;
    const int wv = t >> 6;        // 0..7
    const int wm = wv & 1;        // m-half of the 128-edge tile
    const int wn = wv >> 1;       // 64-col quarter of D1=256
    const int q = lane >> 4;      // 0..3
    const int r = lane & 15;

    const int ebase = blockIdx.x * BM;
    // staging rows for this thread: r0 = t>>3 (rows 0..63), r0+64
    const int r0 = t >> 3;
    const int e1c = (ebase + r0 + 64 < NE) ? (ebase + r0 + 64) : 0;  // ebase+r0 always < NE
    const int ns0 = esrc[ebase + r0];
    const int nd0 = edst[ebase + r0];
    const int ns1 = esrc[e1c];
    const int nd1 = edst[e1c];
    const int gsl = (t & 7) ^ (r0 & 7);  // global chunk this thread fetches (xor swizzle)

    f32x4 acc[4][4];
    #pragma unroll
    for (int a_ = 0; a_ < 4; ++a_)
        #pragma unroll
        for (int b_ = 0; b_ < 4; ++b_) acc[a_][b_] = (f32x4){0.f, 0.f, 0.f, 0.f};

    auto stageA = [&](int kp, char* AbBase) {
        const bool issrc = (kp < 12);
        const int col0 = issrc ? kp * BK : kp * BK - HD;
        #pragma unroll
        for (int i = 0; i < 2; ++i) {
            const int node = i ? (issrc ? ns1 : nd1) : (issrc ? ns0 : nd0);
            bf16_t* lp = (bf16_t*)AbBase + i * 4096 + t * 8;   // lane-linear: t*16 bytes
            if (XPRE) {
                gl2lds16(xb + (size_t)node * HD + col0 + gsl * 8, lp);
            } else {
                const float* gp = xf + (size_t)node * HD + col0 + gsl * 8;
                float4 v0 = ((const float4*)gp)[0];
                float4 v1 = ((const float4*)gp)[1];
                bf16x8 o;
                o[0]=(bf16_t)v0.x; o[1]=(bf16_t)v0.y; o[2]=(bf16_t)v0.z; o[3]=(bf16_t)v0.w;
                o[4]=(bf16_t)v1.x; o[5]=(bf16_t)v1.y; o[6]=(bf16_t)v1.z; o[7]=(bf16_t)v1.w;
                *(bf16x8*)lp = o;
            }
        }
    };

    // prologue: A(0) -> buf0
    stageA(0, smem);

    for (int ks = 0; ks < KSTEPS; ++ks) {
        bf16_t* Ac = (bf16_t*)(smem + ((ks & 1) << 14));
        char*   An = smem + ((~ks & 1) << 14);
        bf16_t* Bl = (bf16_t*)(smem + 32768);

        // B1: waves done reading prev-step LDS; implicit vmcnt(0) drains A(ks),
        // which has had a full MFMA phase + B-stage in flight to cover it.
        __syncthreads();

        // ---- stage B(ks): pre-swizzled w1s streamed lane-linear, fully coalesced ----
        #pragma unroll
        for (int i = 0; i < 4; ++i) {
            const int ci = i * 512 + t;            // chunk = kc*256 + n
            bf16_t* lp = Bl + ci * 8;
            if (WPRE) {
                gl2lds16(w1s + (size_t)ks * 16384 + ci * 8, lp);
            } else {
                const int n = ci & 255, kc = ci >> 8;
                const float* gp = w1f + (size_t)n * TWOH + ks * BK + kc * 8;
                float4 v0 = ((const float4*)gp)[0];
                float4 v1 = ((const float4*)gp)[1];
                bf16x8 o;
                o[0]=(bf16_t)v0.x; o[1]=(bf16_t)v0.y; o[2]=(bf16_t)v0.z; o[3]=(bf16_t)v0.w;
                o[4]=(bf16_t)v1.x; o[5]=(bf16_t)v1.y; o[6]=(bf16_t)v1.z; o[7]=(bf16_t)v1.w;
                *(bf16x8*)lp = o;
            }
        }

        // B2: wait ONLY B(ks) (A(ks+1) not yet issued -> vmcnt(0) == B wait).
        if (XPRE && WPRE)
            asm volatile("s_waitcnt vmcnt(0)\n\ts_barrier" ::: "memory");
        else
            __syncthreads();

        // ---- prefetch A(ks+1) BEFORE the MFMA phase so compute covers the gather ----
        if (ks + 1 < KSTEPS) stageA(ks + 1, An);

        // ---- MFMA inner loop on Ac / Bl ----
        #pragma unroll
        for (int kk = 0; kk < 2; ++kk) {
            bf16x8 af[4];
            const int sl = (kk * 4 + q) ^ (r & 7);   // xor-swizzled slot
            #pragma unroll
            for (int mb = 0; mb < 4; ++mb) {
                const int m = wm * 64 + mb * 16 + r;
                af[mb] = *(const bf16x8*)(Ac + m * 64 + sl * 8);
            }
            #pragma unroll
            for (int nb = 0; nb < 4; ++nb) {
                bf16x8 bfr = *(const bf16x8*)(Bl + (size_t)(((kk * 4 + q) << 8) + wn * 64 + nb * 16 + r) * 8);
                #pragma unroll
                for (int mb = 0; mb < 4; ++mb)
                    acc[mb][nb] = __builtin_amdgcn_mfma_f32_16x16x32_bf16(af[mb], bfr, acc[mb][nb], 0, 0, 0);
            }
        }
    }

    // ---- epilogue: bias + exact gelu -> H (bf16, xor-swizzled) -> GEMM2 -> softmax/CE ----
    bf16_t* Hl = (bf16_t*)smem;
    float* red = (float*)(smem + 32768);

    float bias[4];
    #pragma unroll
    for (int nb = 0; nb < 4; ++nb) bias[nb] = b1[wn * 64 + nb * 16 + r];

    float wnll_t = 0.f, wsum_t = 0.f;
    const int ml2 = t >> 3;       // 0..63 edge within half-tile
    const int p = t & 7;          // 8 threads per edge

    #pragma unroll
    for (int half = 0; half < 2; ++half) {
        __syncthreads();          // drains vmcnt: last prefetch landed before H writes
        if (wm == half) {
            #pragma unroll
            for (int mb = 0; mb < 4; ++mb)
                #pragma unroll
                for (int nb = 0; nb < 4; ++nb)
                    #pragma unroll
                    for (int rr = 0; rr < 4; ++rr) {
                        int ml = mb * 16 + q * 4 + rr;          // 0..63
                        int col = wn * 64 + nb * 16 + r;        // 0..255
                        float v = acc[mb][nb][rr] + bias[nb];
                        float g = 0.5f * v * (1.f + erff(v * 0.70710678118654752f));
                        int swcol = ((((col >> 3) ^ (ml & 7)) << 3) | (col & 7));
                        Hl[ml * 256 + swcol] = (bf16_t)g;
                    }
        }
        __syncthreads();
        float l0 = 0.f, l1 = 0.f;
        #pragma unroll
        for (int j = 0; j < 4; ++j) {
            int cj = p * 4 + j;
            bf16x8 hv = *(const bf16x8*)(Hl + ml2 * 256 + ((cj ^ (ml2 & 7)) << 3));
            const float4* w2a = (const float4*)(w2 + cj * 8);
            const float4* w2b = (const float4*)(w2 + 256 + cj * 8);
            float4 wa0 = w2a[0], wa1 = w2a[1], wb0 = w2b[0], wb1 = w2b[1];
            float hf[8];
            #pragma unroll
            for (int u = 0; u < 8; ++u) hf[u] = (float)hv[u];
            l0 += hf[0]*wa0.x + hf[1]*wa0.y + hf[2]*wa0.z + hf[3]*wa0.w
                + hf[4]*wa1.x + hf[5]*wa1.y + hf[6]*wa1.z + hf[7]*wa1.w;
            l1 += hf[0]*wb0.x + hf[1]*wb0.y + hf[2]*wb0.z + hf[3]*wb0.w
                + hf[4]*wb1.x + hf[5]*wb1.y + hf[6]*wb1.z + hf[7]*wb1.w;
        }
        l0 += __shfl_xor(l0, 1); l0 += __shfl_xor(l0, 2); l0 += __shfl_xor(l0, 4);
        l1 += __shfl_xor(l1, 1); l1 += __shfl_xor(l1, 2); l1 += __shfl_xor(l1, 4);
        const int eg = ebase + half * 64 + ml2;
        if (p == 0 && eg < NE) {
            l0 += b2[0]; l1 += b2[1];
            float mx = fmaxf(l0, l1);
            float e0 = expf(l0 - mx), e1 = expf(l1 - mx);
            float s = e0 + e1;
            float inv = 1.f / s;
            out[1 + 2 * eg] = e0 * inv;
            out[2 + 2 * eg] = e1 * inv;
            int lb = lab[eg];
            float w = cw[lb];
            float lpv = ((lb ? l1 : l0) - mx) - logf(s);
            wnll_t -= w * lpv;
            wsum_t += w;
        }
    }
    // block reduction -> 2 atomics/block
    #pragma unroll
    for (int o = 1; o < 64; o <<= 1) {
        wnll_t += __shfl_xor(wnll_t, o);
        wsum_t += __shfl_xor(wsum_t, o);
    }
    __syncthreads();              // Hl reads done before red writes (red aliases B region)
    if (lane == 0) { red[wv] = wnll_t; red[8 + wv] = wsum_t; }
    __syncthreads();
    if (t == 0) {
        float a_ = 0.f, b_ = 0.f;
        #pragma unroll
        for (int i = 0; i < 8; ++i) { a_ += red[i]; b_ += red[8 + i]; }
        atomicAdd(&accum[0], a_);
        atomicAdd(&accum[1], b_);
    }
}

extern "C" void kernel_launch(void* const* d_in, const int* in_sizes, int n_in,
                              void* d_out, int out_size, void* d_ws, size_t ws_size,
                              hipStream_t stream)
{
    (void)in_sizes; (void)n_in; (void)out_size;
    const float* x  = (const float*)d_in[0];
    const float* W1 = (const float*)d_in[1];
    const float* b1 = (const float*)d_in[2];
    const float* W2 = (const float*)d_in[3];
    const float* b2 = (const float*)d_in[4];
    const float* cw = (const float*)d_in[5];
    const int* esrc = (const int*)d_in[6];
    const int* edst = (const int*)d_in[7];
    const int* lab  = (const int*)d_in[8];
    float* out = (float*)d_out;
    char* ws = (char*)d_ws;

    float* accum = (float*)ws;
    const size_t off_w1 = 256;
    const size_t w1_bytes = (size_t)DD1 * TWOH * 2;     // 786432
    const size_t off_x = off_w1 + w1_bytes;             // 786688 (16B aligned)
    const size_t x_bytes = (size_t)NN * HD * 2;         // 76.8 MB
    bf16_t* w1s = (bf16_t*)(ws + off_w1);
    bf16_t* xb  = (bf16_t*)(ws + off_x);
    const bool wpre = ws_size >= off_w1 + w1_bytes;
    const bool xpre = ws_size >= off_x + x_bytes;

    (void)hipMemsetAsync(accum, 0, 2 * sizeof(float), stream);
    if (wpre) {
        int nsw = KSTEPS * 8 * 256;
        swz_w1_kernel<<<(nsw + 255) / 256, 256, 0, stream>>>(W1, w1s);
    }
    if (xpre) {
        int n16 = NN * HD / 16;
        cvt16_kernel<<<(n16 + 255) / 256, 256, 0, stream>>>(x, xb, n16);
    }

    dim3 grid((NE + BM - 1) / BM);
    if (xpre && wpre)
        fused_edge_mlp<true, true><<<grid, 512, 0, stream>>>(x, xb, W1, w1s, b1, W2, b2, cw, esrc, edst, lab, out, accum);
    else if (wpre)
        fused_edge_mlp<false, true><<<grid, 512, 0, stream>>>(x, xb, W1, w1s, b1, W2, b2, cw, esrc, edst, lab, out, accum);
    else
        fused_edge_mlp<false, false><<<grid, 512, 0, stream>>>(x, xb, W1, w1s, b1, W2, b2, cw, esrc, edst, lab, out, accum);

    finalize_kernel<<<1, 1, 0, stream>>>(out, accum);
}